// Round 4
// baseline (296.912 us; speedup 1.0000x reference)
//
#include <hip/hip_runtime.h>
#include <math.h>

#define R_ROWS 26588
#define S_TOT  13294
#define NHEAD  8
#define NLVL   4
#define EPSF   1e-5f

typedef __attribute__((ext_vector_type(8))) short short8;
typedef __attribute__((ext_vector_type(4))) float f32x4;
typedef __attribute__((ext_vector_type(2))) float f32x2;
typedef unsigned short ushort_t;

__device__ __forceinline__ unsigned short f2bf(float f) {
    unsigned int u = __builtin_bit_cast(unsigned int, f);
    unsigned int r = (u + 0x7FFFu + ((u >> 16) & 1u)) >> 16;   // RNE
    return (unsigned short)r;
}

// ---------------------------------------------------------------------------
// Prep: all six weight transposes (blocks 0..735) + query add/convert
// (blocks 736..7382) in ONE launch.
// ---------------------------------------------------------------------------
__global__ __launch_bounds__(256) void prep_kernel(
    const float* __restrict__ W_val, const float* __restrict__ W_off,
    const float* __restrict__ W_attn, const float* __restrict__ W_out,
    const float* __restrict__ W1, const float* __restrict__ W2,
    ushort_t* __restrict__ wt_val, ushort_t* __restrict__ wt_off,
    ushort_t* __restrict__ wt_attn, ushort_t* __restrict__ wt_out,
    ushort_t* __restrict__ wt_w1, ushort_t* __restrict__ wt_w2,
    const float* __restrict__ query, const float* __restrict__ qpos,
    ushort_t* __restrict__ qry_bf, ushort_t* __restrict__ qsum_bf)
{
    __shared__ ushort_t tt[32][33];
    int bid = blockIdx.x;
    if (bid < 736) {
        const float* src; ushort_t* dst; int K, N, t;
        if (bid < 64)       { src = W_val;  dst = wt_val;  K = 256;  N = 256;  t = bid; }
        else if (bid < 128) { src = W_off;  dst = wt_off;  K = 256;  N = 256;  t = bid - 64; }
        else if (bid < 160) { src = W_attn; dst = wt_attn; K = 256;  N = 128;  t = bid - 128; }
        else if (bid < 224) { src = W_out;  dst = wt_out;  K = 256;  N = 256;  t = bid - 160; }
        else if (bid < 480) { src = W1;     dst = wt_w1;   K = 256;  N = 1024; t = bid - 224; }
        else                { src = W2;     dst = wt_w2;   K = 1024; N = 256;  t = bid - 480; }
        int nt = N / 32;
        int bn = (t % nt) * 32, bk = (t / nt) * 32;
        int x = threadIdx.x & 31;
        int y = threadIdx.x >> 5;
#pragma unroll
        for (int i = 0; i < 4; ++i) {
            int k = y + i * 8;
            tt[x][k] = f2bf(src[(long)(bk + k) * N + bn + x]);
        }
        __syncthreads();
#pragma unroll
        for (int i = 0; i < 4; ++i) {
            int n = y + i * 8;
            dst[(long)(bn + n) * K + bk + x] = tt[n][x];
        }
    } else {
        int i = (bid - 736) * 256 + threadIdx.x;   // < R_ROWS*64 exactly
        float4 a = ((const float4*)query)[i];
        float4 b = ((const float4*)qpos)[i];
        uint2 qa, qs;
        qa.x = (unsigned)f2bf(a.x) | ((unsigned)f2bf(a.y) << 16);
        qa.y = (unsigned)f2bf(a.z) | ((unsigned)f2bf(a.w) << 16);
        qs.x = (unsigned)f2bf(a.x + b.x) | ((unsigned)f2bf(a.y + b.y) << 16);
        qs.y = (unsigned)f2bf(a.z + b.z) | ((unsigned)f2bf(a.w + b.w) << 16);
        ((uint2*)qry_bf)[i] = qa;
        ((uint2*)qsum_bf)[i] = qs;
    }
}

// ---------------------------------------------------------------------------
// Async GEMM core, 128x128 tile, BK=32. TRIPLE-buffered with 2-deep
// prefetch (vmcnt(8)) + 48KB LDS -> 3 blocks/CU (__launch_bounds__(256,3)).
// 3 buffers + 2-deep requires a SECOND barrier at the end of each K-step:
// stage(t+3) (issued at iter t+1) overwrites the buffer read at iter t, so
// all waves must have finished reading tile t first. Barrier skipped once
// no future stage will touch the buffer.
// ---------------------------------------------------------------------------
__device__ __forceinline__ void stage_ab(
    const ushort_t* __restrict__ Arow, const ushort_t* __restrict__ Brow,
    int K, int k0, ushort_t* As, ushort_t* Bs, int wave, int lane)
{
    int quadS = lane & 3;
    int rr = lane >> 2;
#pragma unroll
    for (int inst = 0; inst < 2; ++inst) {
        int base_row = wave * 32 + inst * 16;
        int r = base_row + rr;
        int quadG = quadS ^ ((r >> 1) & 3);
        const ushort_t* gp = Arow + (long)r * K + k0 + quadG * 8;
        __builtin_amdgcn_global_load_lds(
            (const __attribute__((address_space(1))) unsigned int*)gp,
            (__attribute__((address_space(3))) unsigned int*)&As[base_row * 32],
            16, 0, 0);
    }
#pragma unroll
    for (int inst = 0; inst < 2; ++inst) {
        int base_row = wave * 32 + inst * 16;
        int r = base_row + rr;
        int quadG = quadS ^ ((r >> 1) & 3);
        const ushort_t* gp = Brow + (long)r * K + k0 + quadG * 8;
        __builtin_amdgcn_global_load_lds(
            (const __attribute__((address_space(1))) unsigned int*)gp,
            (__attribute__((address_space(3))) unsigned int*)&Bs[base_row * 32],
            16, 0, 0);
    }
}

__device__ __forceinline__ void gemm_body(
    ushort_t* As, ushort_t* Bs,   // flat [3*4096] each
    const ushort_t* __restrict__ A, const ushort_t* __restrict__ Wt,
    const float* __restrict__ bias, void* __restrict__ Cv,
    int M, int N, int K, int bm, int bn, bool out_bf16, bool relu)
{
    const int tid  = threadIdx.x;
    const int wave = tid >> 6;
    const int lane = tid & 63;
    const int l15  = lane & 15;
    const int quad = lane >> 4;
    const int wm   = (wave >> 1) * 64;
    const int wn   = (wave & 1) * 64;

    const ushort_t* Arow = A + (long)bm * K;
    const ushort_t* Brow = Wt + (long)bn * K;

    f32x4 acc[4][4];
#pragma unroll
    for (int i = 0; i < 4; ++i)
#pragma unroll
        for (int j = 0; j < 4; ++j) acc[i][j] = (f32x4)0.0f;

    int aoff[4], boff[4];
#pragma unroll
    for (int mi = 0; mi < 4; ++mi) {
        int r = wm + mi * 16 + l15;
        aoff[mi] = r * 32 + (quad ^ ((r >> 1) & 3)) * 8;
    }
#pragma unroll
    for (int ni = 0; ni < 4; ++ni) {
        int r = wn + ni * 16 + l15;
        boff[ni] = r * 32 + (quad ^ ((r >> 1) & 3)) * 8;
    }

    const int NT = K >> 5;   // always >= 8 here
    stage_ab(Arow, Brow, K, 0,  As,        Bs,        wave, lane);
    stage_ab(Arow, Brow, K, 32, As + 4096, Bs + 4096, wave, lane);
    int cur = 0;
    for (int t = 0; t < NT; ++t) {
        if (t + 2 < NT) {
            int nb = cur + 2; if (nb >= 3) nb -= 3;
            stage_ab(Arow, Brow, K, (t + 2) << 5,
                     As + nb * 4096, Bs + nb * 4096, wave, lane);
            // 4 loads/wave/tile; leave tiles t+1,t+2 (8 ops) in flight.
            asm volatile("s_waitcnt vmcnt(8)" ::: "memory");
        } else if (t + 2 == NT) {
            asm volatile("s_waitcnt vmcnt(4)" ::: "memory");
        } else {
            asm volatile("s_waitcnt vmcnt(0)" ::: "memory");
        }
        asm volatile("s_barrier" ::: "memory");

        const ushort_t* Ab = As + cur * 4096;
        const ushort_t* Bb = Bs + cur * 4096;
        short8 af[4], bf[4];
#pragma unroll
        for (int mi = 0; mi < 4; ++mi) af[mi] = *(const short8*)&Ab[aoff[mi]];
#pragma unroll
        for (int ni = 0; ni < 4; ++ni) bf[ni] = *(const short8*)&Bb[boff[ni]];
#pragma unroll
        for (int mi = 0; mi < 4; ++mi)
#pragma unroll
            for (int ni = 0; ni < 4; ++ni)
                acc[mi][ni] = __builtin_amdgcn_mfma_f32_16x16x32_bf16(
                    af[mi], bf[ni], acc[mi][ni], 0, 0, 0);
        // end-of-step barrier: tile t's buffer gets overwritten by
        // stage(t+3) at the top of the next iteration — every wave must be
        // done reading it first.
        if (t + 3 < NT)
            asm volatile("s_barrier" ::: "memory");
        cur = cur + 1; if (cur >= 3) cur -= 3;
    }

#pragma unroll
    for (int mi = 0; mi < 4; ++mi) {
#pragma unroll
        for (int r = 0; r < 4; ++r) {
            int row = bm + wm + mi * 16 + quad * 4 + r;
            if (row >= M) continue;
#pragma unroll
            for (int ni = 0; ni < 4; ++ni) {
                int col = bn + wn + ni * 16 + l15;
                float vv = acc[mi][ni][r] + bias[col];
                if (relu) vv = fmaxf(vv, 0.f);
                if (out_bf16)
                    ((ushort_t*)Cv)[(long)row * N + col] = f2bf(vv);
                else
                    ((float*)Cv)[(long)row * N + col] = vv;
            }
        }
    }
}

template<bool OUT_BF16, bool RELU>
__global__ __launch_bounds__(256, 3) void gemm_mfma_kernel(
    const ushort_t* __restrict__ A, const ushort_t* __restrict__ Wt,
    const float* __restrict__ bias, void* __restrict__ Cv,
    int M, int N, int K)
{
    __shared__ ushort_t As[3 * 4096];
    __shared__ ushort_t Bs[3 * 4096];
    gemm_body(As, Bs, A, Wt, bias, Cv, M, N, K,
              blockIdx.x * 128, blockIdx.y * 128, OUT_BF16, RELU);
}

// Combined val/off/attn projections. grid = (208, 5).
__global__ __launch_bounds__(256, 3) void proj_kernel(
    const ushort_t* __restrict__ qry_bf, const ushort_t* __restrict__ q_bf,
    const ushort_t* __restrict__ wt_val, const ushort_t* __restrict__ wt_off,
    const ushort_t* __restrict__ wt_attn,
    const float* __restrict__ b_val, const float* __restrict__ b_off,
    const float* __restrict__ b_attn,
    ushort_t* __restrict__ v_bf, float* __restrict__ cb, float* __restrict__ logits)
{
    __shared__ ushort_t As[3 * 4096];
    __shared__ ushort_t Bs[3 * 4096];
    int y = blockIdx.y;
    const ushort_t* A; const ushort_t* Wt; const float* bias;
    void* C; bool outbf; int N, bn;
    if (y < 2)      { A = qry_bf; Wt = wt_val;  bias = b_val;  C = v_bf;   outbf = true;  N = 256; bn = y * 128; }
    else if (y < 4) { A = q_bf;   Wt = wt_off;  bias = b_off;  C = cb;     outbf = false; N = 256; bn = (y - 2) * 128; }
    else            { A = q_bf;   Wt = wt_attn; bias = b_attn; C = logits; outbf = false; N = 128; bn = 0; }
    gemm_body(As, Bs, A, Wt, bias, C, R_ROWS, N, 256, blockIdx.x * 128, bn, outbf, false);
}

// ---------------------------------------------------------------------------
// Fused GEMM (BM=64 rows x full N=256, bf16 A, Wt [256][K]) + residual + LN.
// ---------------------------------------------------------------------------
__device__ __forceinline__ void stage_ln64(
    const ushort_t* __restrict__ Arow, const ushort_t* __restrict__ Brow,
    int K, int k0, ushort_t* As, ushort_t* Bs, int wave, int lane)
{
    int quadS = lane & 3;
    int rr = lane >> 2;
    {   // A tile: 64 rows, wave w stages rows w*16 .. w*16+15
        int base_row = wave * 16;
        int r = base_row + rr;
        int quadG = quadS ^ ((r >> 1) & 3);
        const ushort_t* gp = Arow + (long)r * K + k0 + quadG * 8;
        __builtin_amdgcn_global_load_lds(
            (const __attribute__((address_space(1))) unsigned int*)gp,
            (__attribute__((address_space(3))) unsigned int*)&As[base_row * 32],
            16, 0, 0);
    }
#pragma unroll
    for (int inst = 0; inst < 4; ++inst) {   // B tile: 256 rows, wave stages own slab
        int base_row = wave * 64 + inst * 16;
        int r = base_row + rr;
        int quadG = quadS ^ ((r >> 1) & 3);
        const ushort_t* gp = Brow + (long)r * K + k0 + quadG * 8;
        __builtin_amdgcn_global_load_lds(
            (const __attribute__((address_space(1))) unsigned int*)gp,
            (__attribute__((address_space(3))) unsigned int*)&Bs[base_row * 32],
            16, 0, 0);
    }
}

template<bool DUAL>
__global__ __launch_bounds__(256, 2) void gemm_ln_kernel(
    const ushort_t* __restrict__ A, const ushort_t* __restrict__ Wt,
    const float* __restrict__ bias, const float* __restrict__ resid,
    const float* __restrict__ gam, const float* __restrict__ bet,
    float* __restrict__ outf, ushort_t* __restrict__ outb,
    int M, int K)
{
    __shared__ ushort_t As[3 * 2048];    // 64 x 32 bf16 per buffer
    __shared__ ushort_t Bs[3 * 8192];    // 256 x 32 bf16 per buffer
    __shared__ float s1s[64][4], s2s[64][4];

    const int tid  = threadIdx.x;
    const int wave = tid >> 6;
    const int lane = tid & 63;
    const int l15  = lane & 15;
    const int quad = lane >> 4;
    const int wn   = wave * 64;
    const int bm   = blockIdx.x * 64;

    const ushort_t* Arow = A + (long)bm * K;

    float bias4[4], g4[4], be4[4];
#pragma unroll
    for (int ni = 0; ni < 4; ++ni) {
        int col = wn + ni * 16 + l15;
        bias4[ni] = bias[col];
        g4[ni]    = gam[col];
        be4[ni]   = bet[col];
    }
    float rv[4][4][4];
#pragma unroll
    for (int mi = 0; mi < 4; ++mi)
#pragma unroll
        for (int rr = 0; rr < 4; ++rr) {
            int row = bm + mi * 16 + quad * 4 + rr;
#pragma unroll
            for (int ni = 0; ni < 4; ++ni) {
                int col = wn + ni * 16 + l15;
                rv[mi][rr][ni] = (row < M) ? resid[(long)row * 256 + col] : 0.f;
            }
        }

    f32x4 acc[4][4];
#pragma unroll
    for (int i = 0; i < 4; ++i)
#pragma unroll
        for (int j = 0; j < 4; ++j) acc[i][j] = (f32x4)0.0f;

    int aoff[4], boff[4];
#pragma unroll
    for (int mi = 0; mi < 4; ++mi) {
        int r = mi * 16 + l15;
        aoff[mi] = r * 32 + (quad ^ ((r >> 1) & 3)) * 8;
    }
#pragma unroll
    for (int ni = 0; ni < 4; ++ni) {
        int r = wn + ni * 16 + l15;
        boff[ni] = r * 32 + (quad ^ ((r >> 1) & 3)) * 8;
    }

    const int NT = K >> 5;
    stage_ln64(Arow, Wt, K, 0, As, Bs, wave, lane);
    int cur = 0;
    for (int t = 0; t < NT; ++t) {
        int nxt = cur + 1; if (nxt == 3) nxt = 0;
        if (t + 1 < NT) {
            stage_ln64(Arow, Wt, K, (t + 1) << 5,
                       As + nxt * 2048, Bs + nxt * 8192, wave, lane);
            // exactly 5 loads/wave/tile: leave tile t+1 in flight
            asm volatile("s_waitcnt vmcnt(5)" ::: "memory");
        } else {
            asm volatile("s_waitcnt vmcnt(0)" ::: "memory");
        }
        asm volatile("s_barrier" ::: "memory");

        const ushort_t* Ab = As + cur * 2048;
        const ushort_t* Bb = Bs + cur * 8192;
        short8 af[2], bf[4];
#pragma unroll
        for (int mi = 0; mi < 2; ++mi) af[mi] = *(const short8*)&Ab[aoff[mi]];
#pragma unroll
        for (int ni = 0; ni < 4; ++ni) bf[ni] = *(const short8*)&Bb[boff[ni]];
        short8 af2[2];
#pragma unroll
        for (int mi = 2; mi < 4; ++mi) af2[mi - 2] = *(const short8*)&Ab[aoff[mi]];
#pragma unroll
        for (int mi = 0; mi < 2; ++mi)
#pragma unroll
            for (int ni = 0; ni < 4; ++ni)
                acc[mi][ni] = __builtin_amdgcn_mfma_f32_16x16x32_bf16(
                    af[mi], bf[ni], acc[mi][ni], 0, 0, 0);
#pragma unroll
        for (int mi = 2; mi < 4; ++mi)
#pragma unroll
            for (int ni = 0; ni < 4; ++ni)
                acc[mi][ni] = __builtin_amdgcn_mfma_f32_16x16x32_bf16(
                    af2[mi - 2], bf[ni], acc[mi][ni], 0, 0, 0);
        cur = nxt;
    }

    // ---- epilogue: x = acc + bias + resid; LN over the 256-col rows ----
#pragma unroll
    for (int mi = 0; mi < 4; ++mi)
#pragma unroll
        for (int rr = 0; rr < 4; ++rr) {
            float s1 = 0.f, s2 = 0.f;
#pragma unroll
            for (int ni = 0; ni < 4; ++ni) {
                float x = acc[mi][ni][rr] + bias4[ni] + rv[mi][rr][ni];
                acc[mi][ni][rr] = x;
                s1 += x; s2 += x * x;
            }
#pragma unroll
            for (int o = 1; o < 16; o <<= 1) {
                s1 += __shfl_xor(s1, o);
                s2 += __shfl_xor(s2, o);
            }
            if (l15 == 0) {
                int rl = mi * 16 + quad * 4 + rr;
                s1s[rl][wave] = s1;
                s2s[rl][wave] = s2;
            }
        }
    __syncthreads();
#pragma unroll
    for (int mi = 0; mi < 4; ++mi)
#pragma unroll
        for (int rr = 0; rr < 4; ++rr) {
            int rl  = mi * 16 + quad * 4 + rr;
            int row = bm + rl;
            float t1 = s1s[rl][0] + s1s[rl][1] + s1s[rl][2] + s1s[rl][3];
            float t2 = s2s[rl][0] + s2s[rl][1] + s2s[rl][2] + s2s[rl][3];
            float mean = t1 * (1.f / 256.f);
            float var  = t2 * (1.f / 256.f) - mean * mean;
            float inv  = rsqrtf(var + EPSF);
            if (row < M) {
#pragma unroll
                for (int ni = 0; ni < 4; ++ni) {
                    int col = wn + ni * 16 + l15;
                    float y = (acc[mi][ni][rr] - mean) * inv * g4[ni] + be4[ni];
                    outf[(long)row * 256 + col] = y;
                    if (DUAL) outb[(long)row * 256 + col] = f2bf(y);
                }
            }
        }
}

// ---------------------------------------------------------------------------
// Deformable sampling + fused softmax.
// R9: explicit 2-deep software pipeline over point-pairs — batch p+1's 8
// gathers (and LDS meta reads) are issued BEFORE batch p is consumed, so a
// full batch (~8 loads) is always in flight (compiler emits vmcnt(8) before
// the consume). Accumulation order is bit-identical to the serial version.
// ---------------------------------------------------------------------------
#define DEF_BLOCKS 3328
#define DEF_CHUNK  416

__global__ __launch_bounds__(256, 4) void deform_sample_kernel(
    const ushort_t* __restrict__ v, const float* __restrict__ off,
    const float* __restrict__ logits, const float* __restrict__ vr,
    ushort_t* __restrict__ out)
{
    const int Hs_[4] = {100, 50, 25, 13};
    const int S0_[4] = {0, 10000, 12500, 13125};

    // per local group (64/block): 16 points x {4 weights, 4 byte-offsets},
    // group stride 132 dwords (-> 2-way bank aliasing on reads, free)
    __shared__ float meta[64 * 132];

    int wb  = (blockIdx.x & 7) * DEF_CHUNK + (blockIdx.x >> 3);
    int grp = wb * 64 + (threadIdx.x >> 2);
    int j   = threadIdx.x & 3;
    if (grp >= R_ROWS * NHEAD) return;   // wave-aligned cut (R_ROWS*8 % 16 == 0)
    int h = grp & 7;
    int r = grp >> 3;
    int b = (r >= S_TOT) ? 1 : 0;
    int s = r - b * S_TOT;

    int lq = (s < 10000) ? 0 : (s < 12500) ? 1 : (s < 13125) ? 2 : 3;
    int t  = s - S0_[lq];
    int Wq = Hs_[lq];
    int iy = t / Wq;
    int jx = t - iy * Wq;
    float vx = vr[(b * NLVL + lq) * 2 + 0];
    float vy = vr[(b * NLVL + lq) * 2 + 1];
    float rx = (jx + 0.5f) / (vx * (float)Wq);
    float ry = (iy + 0.5f) / (vy * (float)Wq);

    const float* offp = off + (long)r * 256 + h * 32;
    float4 oa = ((const float4*)offp)[2 * j];
    float4 ob = ((const float4*)offp)[2 * j + 1];
    float4 lg = ((const float4*)(logits + (long)grp * 16))[j];

    float mx = fmaxf(fmaxf(lg.x, lg.y), fmaxf(lg.z, lg.w));
    mx = fmaxf(mx, __shfl_xor(mx, 1));
    mx = fmaxf(mx, __shfl_xor(mx, 2));
    float e0 = __expf(lg.x - mx), e1 = __expf(lg.y - mx);
    float e2 = __expf(lg.z - mx), e3 = __expf(lg.w - mx);
    float sum = e0 + e1 + e2 + e3;
    sum += __shfl_xor(sum, 1);
    sum += __shfl_xor(sum, 2);
    float inv = 1.f / sum;

    const int   H  = Hs_[j];
    const float fH = (float)H;
    const int   s0 = S0_[j];
    const int   boff = b ? (S_TOT * 512) : 0;   // byte offset of batch 1
    float oxs[4] = {oa.x, oa.z, ob.x, ob.z};
    float oys[4] = {oa.y, oa.w, ob.y, ob.w};
    float wts[4] = {e0 * inv, e1 * inv, e2 * inv, e3 * inv};

    float* mg = &meta[(threadIdx.x >> 2) * 132];
#pragma unroll
    for (int i = 0; i < 4; ++i) {
        float x = rx * fH + oxs[i] - 0.5f;
        float y = ry * fH + oys[i] - 0.5f;
        float xf = floorf(x), yf = floorf(y);
        float lx = x - xf, ly = y - yf;
        int x0 = (int)xf, y0 = (int)yf;
        bool xv0 = (x0 >= 0) & (x0 < H);
        bool xv1 = (x0 >= -1) & (x0 < H - 1);
        bool yv0 = (y0 >= 0) & (y0 < H);
        bool yv1 = (y0 >= -1) & (y0 < H - 1);
        float w = wts[i];
        f32x4 w4;
        w4.x = (xv0 & yv0) ? (1.f - lx) * (1.f - ly) * w : 0.f;
        w4.y = (xv1 & yv0) ? lx * (1.f - ly) * w : 0.f;
        w4.z = (xv0 & yv1) ? (1.f - lx) * ly * w : 0.f;
        w4.w = (xv1 & yv1) ? lx * ly * w : 0.f;
        int xc0 = min(max(x0, 0), H - 1), xc1 = min(max(x0 + 1, 0), H - 1);
        int yc0 = min(max(y0, 0), H - 1), yc1 = min(max(y0 + 1, 0), H - 1);
        int4 o4;
        o4.x = ((s0 + yc0 * H + xc0) << 9) + boff;   // byte offsets into v
        o4.y = ((s0 + yc0 * H + xc1) << 9) + boff;
        o4.z = ((s0 + yc1 * H + xc0) << 9) + boff;
        o4.w = ((s0 + yc1 * H + xc1) << 9) + boff;
        // slot pt = i*4 + j reproduces the original (point i, level j2) order
        int pt = i * 4 + j;
        *(f32x4*)&mg[pt * 8]     = w4;
        *(int4*) &mg[pt * 8 + 4] = o4;
    }
    // producer and consumer lanes are in the SAME wave: drain LDS writes,
    // memory clobber stops the compiler from hoisting the reads above.
    asm volatile("s_waitcnt lgkmcnt(0)" ::: "memory");

    const char* vbase = (const char*)v;
    const unsigned loff = (unsigned)(h * 64 + j * 16);   // this lane's 16B slot
    f32x2 acc2[4];
#pragma unroll
    for (int c = 0; c < 4; ++c) acc2[c] = (f32x2)0.0f;

#define FMA4(G, WGT) do {                                                    \
        unsigned uu0 = (G).x, uu1 = (G).y, uu2 = (G).z, uu3 = (G).w;         \
        f32x2 gv;                                                            \
        gv.x = __builtin_bit_cast(float, uu0 << 16);                         \
        gv.y = __builtin_bit_cast(float, uu0 & 0xFFFF0000u);                 \
        acc2[0] += gv * (WGT);                                               \
        gv.x = __builtin_bit_cast(float, uu1 << 16);                         \
        gv.y = __builtin_bit_cast(float, uu1 & 0xFFFF0000u);                 \
        acc2[1] += gv * (WGT);                                               \
        gv.x = __builtin_bit_cast(float, uu2 << 16);                         \
        gv.y = __builtin_bit_cast(float, uu2 & 0xFFFF0000u);                 \
        acc2[2] += gv * (WGT);                                               \
        gv.x = __builtin_bit_cast(float, uu3 << 16);                         \
        gv.y = __builtin_bit_cast(float, uu3 & 0xFFFF0000u);                 \
        acc2[3] += gv * (WGT);                                               \
    } while (0)

    // 2-deep pipeline over point-pairs: gg[2][8] gather regs, wv[2][2]
    // weights; all indices static after full unroll.
    uint4 gg[2][8];
    f32x4 wv[2][2];
    {
        f32x4 wA = *(const f32x4*)&mg[0 * 8];
        int4  oA = *(const int4*) &mg[0 * 8 + 4];
        f32x4 wB = *(const f32x4*)&mg[1 * 8];
        int4  oB = *(const int4*) &mg[1 * 8 + 4];
        wv[0][0] = wA; wv[0][1] = wB;
        gg[0][0] = *(const uint4*)(vbase + ((unsigned)oA.x + loff));
        gg[0][1] = *(const uint4*)(vbase + ((unsigned)oA.y + loff));
        gg[0][2] = *(const uint4*)(vbase + ((unsigned)oA.z + loff));
        gg[0][3] = *(const uint4*)(vbase + ((unsigned)oA.w + loff));
        gg[0][4] = *(const uint4*)(vbase + ((unsigned)oB.x + loff));
        gg[0][5] = *(const uint4*)(vbase + ((unsigned)oB.y + loff));
        gg[0][6] = *(const uint4*)(vbase + ((unsigned)oB.z + loff));
        gg[0][7] = *(const uint4*)(vbase + ((unsigned)oB.w + loff));
    }
#pragma unroll
    for (int pp = 0; pp < 8; ++pp) {
        const int c = pp & 1, n = c ^ 1;
        if (pp < 7) {
            f32x4 wA = *(const f32x4*)&mg[(2 * pp + 2) * 8];
            int4  oA = *(const int4*) &mg[(2 * pp + 2) * 8 + 4];
            f32x4 wB = *(const f32x4*)&mg[(2 * pp + 3) * 8];
            int4  oB = *(const int4*) &mg[(2 * pp + 3) * 8 + 4];
            wv[n][0] = wA; wv[n][1] = wB;
            gg[n][0] = *(const uint4*)(vbase + ((unsigned)oA.x + loff));
            gg[n][1] = *(const uint4*)(vbase + ((unsigned)oA.y + loff));
            gg[n][2] = *(const uint4*)(vbase + ((unsigned)oA.z + loff));
            gg[n][3] = *(const uint4*)(vbase + ((unsigned)oA.w + loff));
            gg[n][4] = *(const uint4*)(vbase + ((unsigned)oB.x + loff));
            gg[n][5] = *(const uint4*)(vbase + ((unsigned)oB.y + loff));
            gg[n][6] = *(const uint4*)(vbase + ((unsigned)oB.z + loff));
            gg[n][7] = *(const uint4*)(vbase + ((unsigned)oB.w + loff));
        }
        FMA4(gg[c][0], wv[c][0].x); FMA4(gg[c][1], wv[c][0].y);
        FMA4(gg[c][2], wv[c][0].z); FMA4(gg[c][3], wv[c][0].w);
        FMA4(gg[c][4], wv[c][1].x); FMA4(gg[c][5], wv[c][1].y);
        FMA4(gg[c][6], wv[c][1].z); FMA4(gg[c][7], wv[c][1].w);
    }
#undef FMA4

    uint4 o;
    o.x = (unsigned)f2bf(acc2[0].x) | ((unsigned)f2bf(acc2[0].y) << 16);
    o.y = (unsigned)f2bf(acc2[1].x) | ((unsigned)f2bf(acc2[1].y) << 16);
    o.z = (unsigned)f2bf(acc2[2].x) | ((unsigned)f2bf(acc2[2].y) << 16);
    o.w = (unsigned)f2bf(acc2[3].x) | ((unsigned)f2bf(acc2[3].y) << 16);
    *(uint4*)&out[(long)r * 256 + h * 32 + j * 8] = o;
}

// ---------------------------------------------------------------------------
extern "C" void kernel_launch(void* const* d_in, const int* in_sizes, int n_in,
                              void* d_out, int out_size, void* d_ws, size_t ws_size,
                              hipStream_t stream)
{
    const float* query  = (const float*)d_in[0];
    const float* qpos   = (const float*)d_in[1];
    const float* vr     = (const float*)d_in[2];
    const float* W_off  = (const float*)d_in[5];
    const float* b_off  = (const float*)d_in[6];
    const float* W_attn = (const float*)d_in[7];
    const float* b_attn = (const float*)d_in[8];
    const float* W_val  = (const float*)d_in[9];
    const float* b_val  = (const float*)d_in[10];
    const float* W_out  = (const float*)d_in[11];
    const float* b_out  = (const float*)d_in[12];
    const float* ln1g   = (const float*)d_in[13];
    const float* ln1b   = (const float*)d_in[14];
    const float* W1     = (const float*)d_in[15];
    const float* b1     = (const float*)d_in[16];
    const float* W2     = (const float*)d_in[17];
    const float* b2     = (const float*)d_in[18];
    const float* ln2g   = (const float*)d_in[19];
    const float* ln2b   = (const float*)d_in[20];
    float* out = (float*)d_out;

    float* ws = (float*)d_ws;
    const long R128 = (long)R_ROWS * 128;
    ushort_t* q_bf    = (ushort_t*)(ws);                 // R x 256 bf16
    ushort_t* qry_bf  = (ushort_t*)(ws + R128);          // R x 256 bf16
    ushort_t* v_bf    = (ushort_t*)(ws + 2 * R128);      // R x 256 bf16
    float*    logits  = ws + 3 * R128;                   // R x 128 f32
    ushort_t* h_bf    = (ushort_t*)(ws);                 // R x 1024 bf16 (overlays above, FF stage)
    float*    cb      = ws + 4 * R128;                   // R x 256 f32: off
    ushort_t* samp_bf = (ushort_t*)(ws + 6 * R128);      // R x 256 bf16: sampled -> x_bf
    float*    xb      = ws + 7 * R128;                   // R x 256 f32: x (LN1 out)
    ushort_t* wt      = (ushort_t*)(ws + 9 * R128);
    ushort_t* wt_val  = wt;                 // 256x256
    ushort_t* wt_off  = wt + 65536;         // 256x256
    ushort_t* wt_attn = wt + 131072;        // 128x256
    ushort_t* wt_out  = wt + 163840;        // 256x256
    ushort_t* wt_w1   = wt + 229376;        // 1024x256
    ushort_t* wt_w2   = wt + 491520;        // 256x1024

    dim3 blk(256);
    const int MB128 = (R_ROWS + 127) / 128;   // 208
    const int MB64  = (R_ROWS + 63) / 64;     // 416

    // 1. prep: weight transposes + q/qsum bf16 conversion
    prep_kernel<<<736 + R_ROWS / 4, blk, 0, stream>>>(
        W_val, W_off, W_attn, W_out, W1, W2,
        wt_val, wt_off, wt_attn, wt_out, wt_w1, wt_w2,
        query, qpos, qry_bf, q_bf);
    // 2. val + off + attn projections
    proj_kernel<<<dim3(MB128, 5), blk, 0, stream>>>(
        qry_bf, q_bf, wt_val, wt_off, wt_attn, b_val, b_off, b_attn,
        v_bf, cb, logits);
    // 3. deformable sampling (+softmax) -> samp_bf
    deform_sample_kernel<<<DEF_BLOCKS, blk, 0, stream>>>(
        v_bf, cb, logits, vr, samp_bf);
    // 4. x = LN(query + samp @ W_out + b_out) -> xb (f32) + samp_bf (bf16)
    gemm_ln_kernel<true><<<MB64, blk, 0, stream>>>(
        samp_bf, wt_out, b_out, query, ln1g, ln1b, xb, samp_bf, R_ROWS, 256);
    // 5. h = relu(x @ W1 + b1) -> h_bf
    gemm_mfma_kernel<true, true><<<dim3(MB128, 8), blk, 0, stream>>>(
        samp_bf, wt_w1, b1, h_bf, R_ROWS, 1024, 256);
    // 6. out = LN(x + h @ W2 + b2)
    gemm_ln_kernel<false><<<MB64, blk, 0, stream>>>(
        h_bf, wt_w2, b2, xb, ln2g, ln2b, out, nullptr, R_ROWS, 1024);
}

// Round 5
// 294.027 us; speedup vs baseline: 1.0098x; 1.0098x over previous
//
#include <hip/hip_runtime.h>
#include <math.h>

#define R_ROWS 26588
#define S_TOT  13294
#define NHEAD  8
#define NLVL   4
#define EPSF   1e-5f

typedef __attribute__((ext_vector_type(8))) short short8;
typedef __attribute__((ext_vector_type(4))) float f32x4;
typedef __attribute__((ext_vector_type(2))) float f32x2;
typedef unsigned short ushort_t;

__device__ __forceinline__ unsigned short f2bf(float f) {
    unsigned int u = __builtin_bit_cast(unsigned int, f);
    unsigned int r = (u + 0x7FFFu + ((u >> 16) & 1u)) >> 16;   // RNE
    return (unsigned short)r;
}

// ---------------------------------------------------------------------------
// Prep: all six weight transposes (blocks 0..735) + query add/convert
// (blocks 736..7382) in ONE launch.
// ---------------------------------------------------------------------------
__global__ __launch_bounds__(256) void prep_kernel(
    const float* __restrict__ W_val, const float* __restrict__ W_off,
    const float* __restrict__ W_attn, const float* __restrict__ W_out,
    const float* __restrict__ W1, const float* __restrict__ W2,
    ushort_t* __restrict__ wt_val, ushort_t* __restrict__ wt_off,
    ushort_t* __restrict__ wt_attn, ushort_t* __restrict__ wt_out,
    ushort_t* __restrict__ wt_w1, ushort_t* __restrict__ wt_w2,
    const float* __restrict__ query, const float* __restrict__ qpos,
    ushort_t* __restrict__ qry_bf, ushort_t* __restrict__ qsum_bf)
{
    __shared__ ushort_t tt[32][33];
    int bid = blockIdx.x;
    if (bid < 736) {
        const float* src; ushort_t* dst; int K, N, t;
        if (bid < 64)       { src = W_val;  dst = wt_val;  K = 256;  N = 256;  t = bid; }
        else if (bid < 128) { src = W_off;  dst = wt_off;  K = 256;  N = 256;  t = bid - 64; }
        else if (bid < 160) { src = W_attn; dst = wt_attn; K = 256;  N = 128;  t = bid - 128; }
        else if (bid < 224) { src = W_out;  dst = wt_out;  K = 256;  N = 256;  t = bid - 160; }
        else if (bid < 480) { src = W1;     dst = wt_w1;   K = 256;  N = 1024; t = bid - 224; }
        else                { src = W2;     dst = wt_w2;   K = 1024; N = 256;  t = bid - 480; }
        int nt = N / 32;
        int bn = (t % nt) * 32, bk = (t / nt) * 32;
        int x = threadIdx.x & 31;
        int y = threadIdx.x >> 5;
#pragma unroll
        for (int i = 0; i < 4; ++i) {
            int k = y + i * 8;
            tt[x][k] = f2bf(src[(long)(bk + k) * N + bn + x]);
        }
        __syncthreads();
#pragma unroll
        for (int i = 0; i < 4; ++i) {
            int n = y + i * 8;
            dst[(long)(bn + n) * K + bk + x] = tt[n][x];
        }
    } else {
        int i = (bid - 736) * 256 + threadIdx.x;   // < R_ROWS*64 exactly
        float4 a = ((const float4*)query)[i];
        float4 b = ((const float4*)qpos)[i];
        uint2 qa, qs;
        qa.x = (unsigned)f2bf(a.x) | ((unsigned)f2bf(a.y) << 16);
        qa.y = (unsigned)f2bf(a.z) | ((unsigned)f2bf(a.w) << 16);
        qs.x = (unsigned)f2bf(a.x + b.x) | ((unsigned)f2bf(a.y + b.y) << 16);
        qs.y = (unsigned)f2bf(a.z + b.z) | ((unsigned)f2bf(a.w + b.w) << 16);
        ((uint2*)qry_bf)[i] = qa;
        ((uint2*)qsum_bf)[i] = qs;
    }
}

// ---------------------------------------------------------------------------
// Async GEMM core, 128x128 tile, BK=32. TRIPLE-buffered with 2-deep
// prefetch (vmcnt(8)) + 48KB LDS -> 3 blocks/CU (__launch_bounds__(256,3)).
// 3 buffers + 2-deep requires a SECOND barrier at the end of each K-step:
// stage(t+3) (issued at iter t+1) overwrites the buffer read at iter t, so
// all waves must have finished reading tile t first. Barrier skipped once
// no future stage will touch the buffer.
// ---------------------------------------------------------------------------
__device__ __forceinline__ void stage_ab(
    const ushort_t* __restrict__ Arow, const ushort_t* __restrict__ Brow,
    int K, int k0, ushort_t* As, ushort_t* Bs, int wave, int lane)
{
    int quadS = lane & 3;
    int rr = lane >> 2;
#pragma unroll
    for (int inst = 0; inst < 2; ++inst) {
        int base_row = wave * 32 + inst * 16;
        int r = base_row + rr;
        int quadG = quadS ^ ((r >> 1) & 3);
        const ushort_t* gp = Arow + (long)r * K + k0 + quadG * 8;
        __builtin_amdgcn_global_load_lds(
            (const __attribute__((address_space(1))) unsigned int*)gp,
            (__attribute__((address_space(3))) unsigned int*)&As[base_row * 32],
            16, 0, 0);
    }
#pragma unroll
    for (int inst = 0; inst < 2; ++inst) {
        int base_row = wave * 32 + inst * 16;
        int r = base_row + rr;
        int quadG = quadS ^ ((r >> 1) & 3);
        const ushort_t* gp = Brow + (long)r * K + k0 + quadG * 8;
        __builtin_amdgcn_global_load_lds(
            (const __attribute__((address_space(1))) unsigned int*)gp,
            (__attribute__((address_space(3))) unsigned int*)&Bs[base_row * 32],
            16, 0, 0);
    }
}

__device__ __forceinline__ void gemm_body(
    ushort_t* As, ushort_t* Bs,   // flat [3*4096] each
    const ushort_t* __restrict__ A, const ushort_t* __restrict__ Wt,
    const float* __restrict__ bias, void* __restrict__ Cv,
    int M, int N, int K, int bm, int bn, bool out_bf16, bool relu)
{
    const int tid  = threadIdx.x;
    const int wave = tid >> 6;
    const int lane = tid & 63;
    const int l15  = lane & 15;
    const int quad = lane >> 4;
    const int wm   = (wave >> 1) * 64;
    const int wn   = (wave & 1) * 64;

    const ushort_t* Arow = A + (long)bm * K;
    const ushort_t* Brow = Wt + (long)bn * K;

    f32x4 acc[4][4];
#pragma unroll
    for (int i = 0; i < 4; ++i)
#pragma unroll
        for (int j = 0; j < 4; ++j) acc[i][j] = (f32x4)0.0f;

    int aoff[4], boff[4];
#pragma unroll
    for (int mi = 0; mi < 4; ++mi) {
        int r = wm + mi * 16 + l15;
        aoff[mi] = r * 32 + (quad ^ ((r >> 1) & 3)) * 8;
    }
#pragma unroll
    for (int ni = 0; ni < 4; ++ni) {
        int r = wn + ni * 16 + l15;
        boff[ni] = r * 32 + (quad ^ ((r >> 1) & 3)) * 8;
    }

    const int NT = K >> 5;   // always >= 8 here
    stage_ab(Arow, Brow, K, 0,  As,        Bs,        wave, lane);
    stage_ab(Arow, Brow, K, 32, As + 4096, Bs + 4096, wave, lane);
    int cur = 0;
    for (int t = 0; t < NT; ++t) {
        if (t + 2 < NT) {
            int nb = cur + 2; if (nb >= 3) nb -= 3;
            stage_ab(Arow, Brow, K, (t + 2) << 5,
                     As + nb * 4096, Bs + nb * 4096, wave, lane);
            // 4 loads/wave/tile; leave tiles t+1,t+2 (8 ops) in flight.
            asm volatile("s_waitcnt vmcnt(8)" ::: "memory");
        } else if (t + 2 == NT) {
            asm volatile("s_waitcnt vmcnt(4)" ::: "memory");
        } else {
            asm volatile("s_waitcnt vmcnt(0)" ::: "memory");
        }
        asm volatile("s_barrier" ::: "memory");

        const ushort_t* Ab = As + cur * 4096;
        const ushort_t* Bb = Bs + cur * 4096;
        short8 af[4], bf[4];
#pragma unroll
        for (int mi = 0; mi < 4; ++mi) af[mi] = *(const short8*)&Ab[aoff[mi]];
#pragma unroll
        for (int ni = 0; ni < 4; ++ni) bf[ni] = *(const short8*)&Bb[boff[ni]];
#pragma unroll
        for (int mi = 0; mi < 4; ++mi)
#pragma unroll
            for (int ni = 0; ni < 4; ++ni)
                acc[mi][ni] = __builtin_amdgcn_mfma_f32_16x16x32_bf16(
                    af[mi], bf[ni], acc[mi][ni], 0, 0, 0);
        // end-of-step barrier: tile t's buffer gets overwritten by
        // stage(t+3) at the top of the next iteration — every wave must be
        // done reading it first.
        if (t + 3 < NT)
            asm volatile("s_barrier" ::: "memory");
        cur = cur + 1; if (cur >= 3) cur -= 3;
    }

#pragma unroll
    for (int mi = 0; mi < 4; ++mi) {
#pragma unroll
        for (int r = 0; r < 4; ++r) {
            int row = bm + wm + mi * 16 + quad * 4 + r;
            if (row >= M) continue;
#pragma unroll
            for (int ni = 0; ni < 4; ++ni) {
                int col = bn + wn + ni * 16 + l15;
                float vv = acc[mi][ni][r] + bias[col];
                if (relu) vv = fmaxf(vv, 0.f);
                if (out_bf16)
                    ((ushort_t*)Cv)[(long)row * N + col] = f2bf(vv);
                else
                    ((float*)Cv)[(long)row * N + col] = vv;
            }
        }
    }
}

template<bool OUT_BF16, bool RELU>
__global__ __launch_bounds__(256, 3) void gemm_mfma_kernel(
    const ushort_t* __restrict__ A, const ushort_t* __restrict__ Wt,
    const float* __restrict__ bias, void* __restrict__ Cv,
    int M, int N, int K)
{
    __shared__ ushort_t As[3 * 4096];
    __shared__ ushort_t Bs[3 * 4096];
    gemm_body(As, Bs, A, Wt, bias, Cv, M, N, K,
              blockIdx.x * 128, blockIdx.y * 128, OUT_BF16, RELU);
}

// Combined val/off/attn projections. grid = (208, 5).
__global__ __launch_bounds__(256, 3) void proj_kernel(
    const ushort_t* __restrict__ qry_bf, const ushort_t* __restrict__ q_bf,
    const ushort_t* __restrict__ wt_val, const ushort_t* __restrict__ wt_off,
    const ushort_t* __restrict__ wt_attn,
    const float* __restrict__ b_val, const float* __restrict__ b_off,
    const float* __restrict__ b_attn,
    ushort_t* __restrict__ v_bf, float* __restrict__ cb, float* __restrict__ logits)
{
    __shared__ ushort_t As[3 * 4096];
    __shared__ ushort_t Bs[3 * 4096];
    int y = blockIdx.y;
    const ushort_t* A; const ushort_t* Wt; const float* bias;
    void* C; bool outbf; int N, bn;
    if (y < 2)      { A = qry_bf; Wt = wt_val;  bias = b_val;  C = v_bf;   outbf = true;  N = 256; bn = y * 128; }
    else if (y < 4) { A = q_bf;   Wt = wt_off;  bias = b_off;  C = cb;     outbf = false; N = 256; bn = (y - 2) * 128; }
    else            { A = q_bf;   Wt = wt_attn; bias = b_attn; C = logits; outbf = false; N = 128; bn = 0; }
    gemm_body(As, Bs, A, Wt, bias, C, R_ROWS, N, 256, blockIdx.x * 128, bn, outbf, false);
}

// ---------------------------------------------------------------------------
// Fused GEMM (BM=64 rows x full N=256, bf16 A, Wt [256][K]) + residual + LN.
// (R3 verbatim — the R4 af/af2 split regressed ~4 µs, reverted.)
// ---------------------------------------------------------------------------
__device__ __forceinline__ void stage_ln64(
    const ushort_t* __restrict__ Arow, const ushort_t* __restrict__ Brow,
    int K, int k0, ushort_t* As, ushort_t* Bs, int wave, int lane)
{
    int quadS = lane & 3;
    int rr = lane >> 2;
    {   // A tile: 64 rows, wave w stages rows w*16 .. w*16+15
        int base_row = wave * 16;
        int r = base_row + rr;
        int quadG = quadS ^ ((r >> 1) & 3);
        const ushort_t* gp = Arow + (long)r * K + k0 + quadG * 8;
        __builtin_amdgcn_global_load_lds(
            (const __attribute__((address_space(1))) unsigned int*)gp,
            (__attribute__((address_space(3))) unsigned int*)&As[base_row * 32],
            16, 0, 0);
    }
#pragma unroll
    for (int inst = 0; inst < 4; ++inst) {   // B tile: 256 rows, wave stages own slab
        int base_row = wave * 64 + inst * 16;
        int r = base_row + rr;
        int quadG = quadS ^ ((r >> 1) & 3);
        const ushort_t* gp = Brow + (long)r * K + k0 + quadG * 8;
        __builtin_amdgcn_global_load_lds(
            (const __attribute__((address_space(1))) unsigned int*)gp,
            (__attribute__((address_space(3))) unsigned int*)&Bs[base_row * 32],
            16, 0, 0);
    }
}

template<bool DUAL>
__global__ __launch_bounds__(256, 2) void gemm_ln_kernel(
    const ushort_t* __restrict__ A, const ushort_t* __restrict__ Wt,
    const float* __restrict__ bias, const float* __restrict__ resid,
    const float* __restrict__ gam, const float* __restrict__ bet,
    float* __restrict__ outf, ushort_t* __restrict__ outb,
    int M, int K)
{
    __shared__ ushort_t As[3 * 2048];    // 64 x 32 bf16 per buffer
    __shared__ ushort_t Bs[3 * 8192];    // 256 x 32 bf16 per buffer
    __shared__ float s1s[64][4], s2s[64][4];

    const int tid  = threadIdx.x;
    const int wave = tid >> 6;
    const int lane = tid & 63;
    const int l15  = lane & 15;
    const int quad = lane >> 4;
    const int wn   = wave * 64;
    const int bm   = blockIdx.x * 64;

    const ushort_t* Arow = A + (long)bm * K;

    float bias4[4], g4[4], be4[4];
#pragma unroll
    for (int ni = 0; ni < 4; ++ni) {
        int col = wn + ni * 16 + l15;
        bias4[ni] = bias[col];
        g4[ni]    = gam[col];
        be4[ni]   = bet[col];
    }
    float rv[4][4][4];
#pragma unroll
    for (int mi = 0; mi < 4; ++mi)
#pragma unroll
        for (int rr = 0; rr < 4; ++rr) {
            int row = bm + mi * 16 + quad * 4 + rr;
#pragma unroll
            for (int ni = 0; ni < 4; ++ni) {
                int col = wn + ni * 16 + l15;
                rv[mi][rr][ni] = (row < M) ? resid[(long)row * 256 + col] : 0.f;
            }
        }

    f32x4 acc[4][4];
#pragma unroll
    for (int i = 0; i < 4; ++i)
#pragma unroll
        for (int j = 0; j < 4; ++j) acc[i][j] = (f32x4)0.0f;

    int aoff[4], boff[4];
#pragma unroll
    for (int mi = 0; mi < 4; ++mi) {
        int r = mi * 16 + l15;
        aoff[mi] = r * 32 + (quad ^ ((r >> 1) & 3)) * 8;
    }
#pragma unroll
    for (int ni = 0; ni < 4; ++ni) {
        int r = wn + ni * 16 + l15;
        boff[ni] = r * 32 + (quad ^ ((r >> 1) & 3)) * 8;
    }

    const int NT = K >> 5;
    stage_ln64(Arow, Wt, K, 0, As, Bs, wave, lane);
    int cur = 0;
    for (int t = 0; t < NT; ++t) {
        int nxt = cur + 1; if (nxt == 3) nxt = 0;
        if (t + 1 < NT) {
            stage_ln64(Arow, Wt, K, (t + 1) << 5,
                       As + nxt * 2048, Bs + nxt * 8192, wave, lane);
            // exactly 5 loads/wave/tile: leave tile t+1 in flight
            asm volatile("s_waitcnt vmcnt(5)" ::: "memory");
        } else {
            asm volatile("s_waitcnt vmcnt(0)" ::: "memory");
        }
        asm volatile("s_barrier" ::: "memory");

        const ushort_t* Ab = As + cur * 2048;
        const ushort_t* Bb = Bs + cur * 8192;
        short8 af[4], bf[4];
#pragma unroll
        for (int mi = 0; mi < 4; ++mi) af[mi] = *(const short8*)&Ab[aoff[mi]];
#pragma unroll
        for (int ni = 0; ni < 4; ++ni) bf[ni] = *(const short8*)&Bb[boff[ni]];
#pragma unroll
        for (int mi = 0; mi < 4; ++mi)
#pragma unroll
            for (int ni = 0; ni < 4; ++ni)
                acc[mi][ni] = __builtin_amdgcn_mfma_f32_16x16x32_bf16(
                    af[mi], bf[ni], acc[mi][ni], 0, 0, 0);
        cur = nxt;
    }

    // ---- epilogue: x = acc + bias + resid; LN over the 256-col rows ----
#pragma unroll
    for (int mi = 0; mi < 4; ++mi)
#pragma unroll
        for (int rr = 0; rr < 4; ++rr) {
            float s1 = 0.f, s2 = 0.f;
#pragma unroll
            for (int ni = 0; ni < 4; ++ni) {
                float x = acc[mi][ni][rr] + bias4[ni] + rv[mi][rr][ni];
                acc[mi][ni][rr] = x;
                s1 += x; s2 += x * x;
            }
#pragma unroll
            for (int o = 1; o < 16; o <<= 1) {
                s1 += __shfl_xor(s1, o);
                s2 += __shfl_xor(s2, o);
            }
            if (l15 == 0) {
                int rl = mi * 16 + quad * 4 + rr;
                s1s[rl][wave] = s1;
                s2s[rl][wave] = s2;
            }
        }
    __syncthreads();
#pragma unroll
    for (int mi = 0; mi < 4; ++mi)
#pragma unroll
        for (int rr = 0; rr < 4; ++rr) {
            int rl  = mi * 16 + quad * 4 + rr;
            int row = bm + rl;
            float t1 = s1s[rl][0] + s1s[rl][1] + s1s[rl][2] + s1s[rl][3];
            float t2 = s2s[rl][0] + s2s[rl][1] + s2s[rl][2] + s2s[rl][3];
            float mean = t1 * (1.f / 256.f);
            float var  = t2 * (1.f / 256.f) - mean * mean;
            float inv  = rsqrtf(var + EPSF);
            if (row < M) {
#pragma unroll
                for (int ni = 0; ni < 4; ++ni) {
                    int col = wn + ni * 16 + l15;
                    float y = (acc[mi][ni][rr] - mean) * inv * g4[ni] + be4[ni];
                    outf[(long)row * 256 + col] = y;
                    if (DUAL) outb[(long)row * 256 + col] = f2bf(y);
                }
            }
        }
}

// ---------------------------------------------------------------------------
// Deformable sampling + fused softmax.
// R10: the R9 2-deep pipeline, now PINNED with sched_barrier(0) between the
// batch-(n+1) prefetch and the batch-n consume. R9's pipeline was undone by
// the scheduler (VGPR stayed 52 -> loads sunk to consumers). The fence
// forces load-issue before consume, so the auto-waitcnt becomes vmcnt(8)
// and a full 8-gather batch stays in flight. Accumulation order unchanged.
// ---------------------------------------------------------------------------
#define DEF_BLOCKS 3328
#define DEF_CHUNK  416

__global__ __launch_bounds__(256, 4) void deform_sample_kernel(
    const ushort_t* __restrict__ v, const float* __restrict__ off,
    const float* __restrict__ logits, const float* __restrict__ vr,
    ushort_t* __restrict__ out)
{
    const int Hs_[4] = {100, 50, 25, 13};
    const int S0_[4] = {0, 10000, 12500, 13125};

    // per local group (64/block): 16 points x {4 weights, 4 byte-offsets},
    // group stride 132 dwords (-> 2-way bank aliasing on reads, free)
    __shared__ float meta[64 * 132];

    int wb  = (blockIdx.x & 7) * DEF_CHUNK + (blockIdx.x >> 3);
    int grp = wb * 64 + (threadIdx.x >> 2);
    int j   = threadIdx.x & 3;
    if (grp >= R_ROWS * NHEAD) return;   // wave-aligned cut (R_ROWS*8 % 16 == 0)
    int h = grp & 7;
    int r = grp >> 3;
    int b = (r >= S_TOT) ? 1 : 0;
    int s = r - b * S_TOT;

    int lq = (s < 10000) ? 0 : (s < 12500) ? 1 : (s < 13125) ? 2 : 3;
    int t  = s - S0_[lq];
    int Wq = Hs_[lq];
    int iy = t / Wq;
    int jx = t - iy * Wq;
    float vx = vr[(b * NLVL + lq) * 2 + 0];
    float vy = vr[(b * NLVL + lq) * 2 + 1];
    float rx = (jx + 0.5f) / (vx * (float)Wq);
    float ry = (iy + 0.5f) / (vy * (float)Wq);

    const float* offp = off + (long)r * 256 + h * 32;
    float4 oa = ((const float4*)offp)[2 * j];
    float4 ob = ((const float4*)offp)[2 * j + 1];
    float4 lg = ((const float4*)(logits + (long)grp * 16))[j];

    float mx = fmaxf(fmaxf(lg.x, lg.y), fmaxf(lg.z, lg.w));
    mx = fmaxf(mx, __shfl_xor(mx, 1));
    mx = fmaxf(mx, __shfl_xor(mx, 2));
    float e0 = __expf(lg.x - mx), e1 = __expf(lg.y - mx);
    float e2 = __expf(lg.z - mx), e3 = __expf(lg.w - mx);
    float sum = e0 + e1 + e2 + e3;
    sum += __shfl_xor(sum, 1);
    sum += __shfl_xor(sum, 2);
    float inv = 1.f / sum;

    const int   H  = Hs_[j];
    const float fH = (float)H;
    const int   s0 = S0_[j];
    const int   boff = b ? (S_TOT * 512) : 0;   // byte offset of batch 1
    float oxs[4] = {oa.x, oa.z, ob.x, ob.z};
    float oys[4] = {oa.y, oa.w, ob.y, ob.w};
    float wts[4] = {e0 * inv, e1 * inv, e2 * inv, e3 * inv};

    float* mg = &meta[(threadIdx.x >> 2) * 132];
#pragma unroll
    for (int i = 0; i < 4; ++i) {
        float x = rx * fH + oxs[i] - 0.5f;
        float y = ry * fH + oys[i] - 0.5f;
        float xf = floorf(x), yf = floorf(y);
        float lx = x - xf, ly = y - yf;
        int x0 = (int)xf, y0 = (int)yf;
        bool xv0 = (x0 >= 0) & (x0 < H);
        bool xv1 = (x0 >= -1) & (x0 < H - 1);
        bool yv0 = (y0 >= 0) & (y0 < H);
        bool yv1 = (y0 >= -1) & (y0 < H - 1);
        float w = wts[i];
        f32x4 w4;
        w4.x = (xv0 & yv0) ? (1.f - lx) * (1.f - ly) * w : 0.f;
        w4.y = (xv1 & yv0) ? lx * (1.f - ly) * w : 0.f;
        w4.z = (xv0 & yv1) ? (1.f - lx) * ly * w : 0.f;
        w4.w = (xv1 & yv1) ? lx * ly * w : 0.f;
        int xc0 = min(max(x0, 0), H - 1), xc1 = min(max(x0 + 1, 0), H - 1);
        int yc0 = min(max(y0, 0), H - 1), yc1 = min(max(y0 + 1, 0), H - 1);
        int4 o4;
        o4.x = ((s0 + yc0 * H + xc0) << 9) + boff;   // byte offsets into v
        o4.y = ((s0 + yc0 * H + xc1) << 9) + boff;
        o4.z = ((s0 + yc1 * H + xc0) << 9) + boff;
        o4.w = ((s0 + yc1 * H + xc1) << 9) + boff;
        // slot pt = i*4 + j reproduces the original (point i, level j2) order
        int pt = i * 4 + j;
        *(f32x4*)&mg[pt * 8]     = w4;
        *(int4*) &mg[pt * 8 + 4] = o4;
    }
    // producer and consumer lanes are in the SAME wave: drain LDS writes,
    // memory clobber stops the compiler from hoisting the reads above.
    asm volatile("s_waitcnt lgkmcnt(0)" ::: "memory");

    const char* vbase = (const char*)v;
    const unsigned loff = (unsigned)(h * 64 + j * 16);   // this lane's 16B slot
    f32x2 acc2[4];
#pragma unroll
    for (int c = 0; c < 4; ++c) acc2[c] = (f32x2)0.0f;

#define FMA4(G, WGT) do {                                                    \
        unsigned uu0 = (G).x, uu1 = (G).y, uu2 = (G).z, uu3 = (G).w;         \
        f32x2 gv;                                                            \
        gv.x = __builtin_bit_cast(float, uu0 << 16);                         \
        gv.y = __builtin_bit_cast(float, uu0 & 0xFFFF0000u);                 \
        acc2[0] += gv * (WGT);                                               \
        gv.x = __builtin_bit_cast(float, uu1 << 16);                         \
        gv.y = __builtin_bit_cast(float, uu1 & 0xFFFF0000u);                 \
        acc2[1] += gv * (WGT);                                               \
        gv.x = __builtin_bit_cast(float, uu2 << 16);                         \
        gv.y = __builtin_bit_cast(float, uu2 & 0xFFFF0000u);                 \
        acc2[2] += gv * (WGT);                                               \
        gv.x = __builtin_bit_cast(float, uu3 << 16);                         \
        gv.y = __builtin_bit_cast(float, uu3 & 0xFFFF0000u);                 \
        acc2[3] += gv * (WGT);                                               \
    } while (0)

    // 2-deep pipeline over point-pairs: gg[2][8] gather regs, wv[2][2]
    // weights; all indices static after full unroll; order pinned by
    // sched_barrier(0) so the scheduler cannot sink the prefetch.
    uint4 gg[2][8];
    f32x4 wv[2][2];
    {
        f32x4 wA = *(const f32x4*)&mg[0 * 8];
        int4  oA = *(const int4*) &mg[0 * 8 + 4];
        f32x4 wB = *(const f32x4*)&mg[1 * 8];
        int4  oB = *(const int4*) &mg[1 * 8 + 4];
        wv[0][0] = wA; wv[0][1] = wB;
        gg[0][0] = *(const uint4*)(vbase + ((unsigned)oA.x + loff));
        gg[0][1] = *(const uint4*)(vbase + ((unsigned)oA.y + loff));
        gg[0][2] = *(const uint4*)(vbase + ((unsigned)oA.z + loff));
        gg[0][3] = *(const uint4*)(vbase + ((unsigned)oA.w + loff));
        gg[0][4] = *(const uint4*)(vbase + ((unsigned)oB.x + loff));
        gg[0][5] = *(const uint4*)(vbase + ((unsigned)oB.y + loff));
        gg[0][6] = *(const uint4*)(vbase + ((unsigned)oB.z + loff));
        gg[0][7] = *(const uint4*)(vbase + ((unsigned)oB.w + loff));
    }
#pragma unroll
    for (int pp = 0; pp < 8; ++pp) {
        const int c = pp & 1, n = c ^ 1;
        if (pp < 7) {
            f32x4 wA = *(const f32x4*)&mg[(2 * pp + 2) * 8];
            int4  oA = *(const int4*) &mg[(2 * pp + 2) * 8 + 4];
            f32x4 wB = *(const f32x4*)&mg[(2 * pp + 3) * 8];
            int4  oB = *(const int4*) &mg[(2 * pp + 3) * 8 + 4];
            wv[n][0] = wA; wv[n][1] = wB;
            gg[n][0] = *(const uint4*)(vbase + ((unsigned)oA.x + loff));
            gg[n][1] = *(const uint4*)(vbase + ((unsigned)oA.y + loff));
            gg[n][2] = *(const uint4*)(vbase + ((unsigned)oA.z + loff));
            gg[n][3] = *(const uint4*)(vbase + ((unsigned)oA.w + loff));
            gg[n][4] = *(const uint4*)(vbase + ((unsigned)oB.x + loff));
            gg[n][5] = *(const uint4*)(vbase + ((unsigned)oB.y + loff));
            gg[n][6] = *(const uint4*)(vbase + ((unsigned)oB.z + loff));
            gg[n][7] = *(const uint4*)(vbase + ((unsigned)oB.w + loff));
        }
        // pin: prefetch above must be EMITTED before the consume below, so
        // the auto s_waitcnt before gg[c] use counts 8 outstanding loads.
        __builtin_amdgcn_sched_barrier(0);
        FMA4(gg[c][0], wv[c][0].x); FMA4(gg[c][1], wv[c][0].y);
        FMA4(gg[c][2], wv[c][0].z); FMA4(gg[c][3], wv[c][0].w);
        FMA4(gg[c][4], wv[c][1].x); FMA4(gg[c][5], wv[c][1].y);
        FMA4(gg[c][6], wv[c][1].z); FMA4(gg[c][7], wv[c][1].w);
    }
#undef FMA4

    uint4 o;
    o.x = (unsigned)f2bf(acc2[0].x) | ((unsigned)f2bf(acc2[0].y) << 16);
    o.y = (unsigned)f2bf(acc2[1].x) | ((unsigned)f2bf(acc2[1].y) << 16);
    o.z = (unsigned)f2bf(acc2[2].x) | ((unsigned)f2bf(acc2[2].y) << 16);
    o.w = (unsigned)f2bf(acc2[3].x) | ((unsigned)f2bf(acc2[3].y) << 16);
    *(uint4*)&out[(long)r * 256 + h * 32 + j * 8] = o;
}

// ---------------------------------------------------------------------------
extern "C" void kernel_launch(void* const* d_in, const int* in_sizes, int n_in,
                              void* d_out, int out_size, void* d_ws, size_t ws_size,
                              hipStream_t stream)
{
    const float* query  = (const float*)d_in[0];
    const float* qpos   = (const float*)d_in[1];
    const float* vr     = (const float*)d_in[2];
    const float* W_off  = (const float*)d_in[5];
    const float* b_off  = (const float*)d_in[6];
    const float* W_attn = (const float*)d_in[7];
    const float* b_attn = (const float*)d_in[8];
    const float* W_val  = (const float*)d_in[9];
    const float* b_val  = (const float*)d_in[10];
    const float* W_out  = (const float*)d_in[11];
    const float* b_out  = (const float*)d_in[12];
    const float* ln1g   = (const float*)d_in[13];
    const float* ln1b   = (const float*)d_in[14];
    const float* W1     = (const float*)d_in[15];
    const float* b1     = (const float*)d_in[16];
    const float* W2     = (const float*)d_in[17];
    const float* b2     = (const float*)d_in[18];
    const float* ln2g   = (const float*)d_in[19];
    const float* ln2b   = (const float*)d_in[20];
    float* out = (float*)d_out;

    float* ws = (float*)d_ws;
    const long R128 = (long)R_ROWS * 128;
    ushort_t* q_bf    = (ushort_t*)(ws);                 // R x 256 bf16
    ushort_t* qry_bf  = (ushort_t*)(ws + R128);          // R x 256 bf16
    ushort_t* v_bf    = (ushort_t*)(ws + 2 * R128);      // R x 256 bf16
    float*    logits  = ws + 3 * R128;                   // R x 128 f32
    ushort_t* h_bf    = (ushort_t*)(ws);                 // R x 1024 bf16 (overlays above, FF stage)
    float*    cb      = ws + 4 * R128;                   // R x 256 f32: off
    ushort_t* samp_bf = (ushort_t*)(ws + 6 * R128);      // R x 256 bf16: sampled -> x_bf
    float*    xb      = ws + 7 * R128;                   // R x 256 f32: x (LN1 out)
    ushort_t* wt      = (ushort_t*)(ws + 9 * R128);
    ushort_t* wt_val  = wt;                 // 256x256
    ushort_t* wt_off  = wt + 65536;         // 256x256
    ushort_t* wt_attn = wt + 131072;        // 128x256
    ushort_t* wt_out  = wt + 163840;        // 256x256
    ushort_t* wt_w1   = wt + 229376;        // 1024x256
    ushort_t* wt_w2   = wt + 491520;        // 256x1024

    dim3 blk(256);
    const int MB128 = (R_ROWS + 127) / 128;   // 208
    const int MB64  = (R_ROWS + 63) / 64;     // 416

    // 1. prep: weight transposes + q/qsum bf16 conversion
    prep_kernel<<<736 + R_ROWS / 4, blk, 0, stream>>>(
        W_val, W_off, W_attn, W_out, W1, W2,
        wt_val, wt_off, wt_attn, wt_out, wt_w1, wt_w2,
        query, qpos, qry_bf, q_bf);
    // 2. val + off + attn projections
    proj_kernel<<<dim3(MB128, 5), blk, 0, stream>>>(
        qry_bf, q_bf, wt_val, wt_off, wt_attn, b_val, b_off, b_attn,
        v_bf, cb, logits);
    // 3. deformable sampling (+softmax) -> samp_bf
    deform_sample_kernel<<<DEF_BLOCKS, blk, 0, stream>>>(
        v_bf, cb, logits, vr, samp_bf);
    // 4. x = LN(query + samp @ W_out + b_out) -> xb (f32) + samp_bf (bf16)
    gemm_ln_kernel<true><<<MB64, blk, 0, stream>>>(
        samp_bf, wt_out, b_out, query, ln1g, ln1b, xb, samp_bf, R_ROWS, 256);
    // 5. h = relu(x @ W1 + b1) -> h_bf
    gemm_mfma_kernel<true, true><<<dim3(MB128, 8), blk, 0, stream>>>(
        samp_bf, wt_w1, b1, h_bf, R_ROWS, 1024, 256);
    // 6. out = LN(x + h @ W2 + b2)
    gemm_ln_kernel<false><<<MB64, blk, 0, stream>>>(
        h_bf, wt_w2, b2, xb, ln2g, ln2b, out, nullptr, R_ROWS, 1024);
}

// Round 6
// 287.440 us; speedup vs baseline: 1.0330x; 1.0229x over previous
//
#include <hip/hip_runtime.h>
#include <math.h>

#define R_ROWS 26588
#define S_TOT  13294
#define NHEAD  8
#define NLVL   4
#define EPSF   1e-5f

typedef __attribute__((ext_vector_type(8))) short short8;
typedef __attribute__((ext_vector_type(4))) float f32x4;
typedef __attribute__((ext_vector_type(2))) float f32x2;
typedef unsigned short ushort_t;

__device__ __forceinline__ unsigned short f2bf(float f) {
    unsigned int u = __builtin_bit_cast(unsigned int, f);
    unsigned int r = (u + 0x7FFFu + ((u >> 16) & 1u)) >> 16;   // RNE
    return (unsigned short)r;
}

// ---------------------------------------------------------------------------
// Prep: all six weight transposes (blocks 0..735) + query add/convert
// (blocks 736..7382) in ONE launch.
// ---------------------------------------------------------------------------
__global__ __launch_bounds__(256) void prep_kernel(
    const float* __restrict__ W_val, const float* __restrict__ W_off,
    const float* __restrict__ W_attn, const float* __restrict__ W_out,
    const float* __restrict__ W1, const float* __restrict__ W2,
    ushort_t* __restrict__ wt_val, ushort_t* __restrict__ wt_off,
    ushort_t* __restrict__ wt_attn, ushort_t* __restrict__ wt_out,
    ushort_t* __restrict__ wt_w1, ushort_t* __restrict__ wt_w2,
    const float* __restrict__ query, const float* __restrict__ qpos,
    ushort_t* __restrict__ qry_bf, ushort_t* __restrict__ qsum_bf)
{
    __shared__ ushort_t tt[32][33];
    int bid = blockIdx.x;
    if (bid < 736) {
        const float* src; ushort_t* dst; int K, N, t;
        if (bid < 64)       { src = W_val;  dst = wt_val;  K = 256;  N = 256;  t = bid; }
        else if (bid < 128) { src = W_off;  dst = wt_off;  K = 256;  N = 256;  t = bid - 64; }
        else if (bid < 160) { src = W_attn; dst = wt_attn; K = 256;  N = 128;  t = bid - 128; }
        else if (bid < 224) { src = W_out;  dst = wt_out;  K = 256;  N = 256;  t = bid - 160; }
        else if (bid < 480) { src = W1;     dst = wt_w1;   K = 256;  N = 1024; t = bid - 224; }
        else                { src = W2;     dst = wt_w2;   K = 1024; N = 256;  t = bid - 480; }
        int nt = N / 32;
        int bn = (t % nt) * 32, bk = (t / nt) * 32;
        int x = threadIdx.x & 31;
        int y = threadIdx.x >> 5;
#pragma unroll
        for (int i = 0; i < 4; ++i) {
            int k = y + i * 8;
            tt[x][k] = f2bf(src[(long)(bk + k) * N + bn + x]);
        }
        __syncthreads();
#pragma unroll
        for (int i = 0; i < 4; ++i) {
            int n = y + i * 8;
            dst[(long)(bn + n) * K + bk + x] = tt[n][x];
        }
    } else {
        int i = (bid - 736) * 256 + threadIdx.x;   // < R_ROWS*64 exactly
        float4 a = ((const float4*)query)[i];
        float4 b = ((const float4*)qpos)[i];
        uint2 qa, qs;
        qa.x = (unsigned)f2bf(a.x) | ((unsigned)f2bf(a.y) << 16);
        qa.y = (unsigned)f2bf(a.z) | ((unsigned)f2bf(a.w) << 16);
        qs.x = (unsigned)f2bf(a.x + b.x) | ((unsigned)f2bf(a.y + b.y) << 16);
        qs.y = (unsigned)f2bf(a.z + b.z) | ((unsigned)f2bf(a.w + b.w) << 16);
        ((uint2*)qry_bf)[i] = qa;
        ((uint2*)qsum_bf)[i] = qs;
    }
}

// ---------------------------------------------------------------------------
// Async GEMM core, 128x128 tile, BK=32. TRIPLE-buffered with 2-deep
// prefetch (vmcnt(8)) + 48KB LDS -> 3 blocks/CU (__launch_bounds__(256,3)).
// 3 buffers + 2-deep requires a SECOND barrier at the end of each K-step:
// stage(t+3) (issued at iter t+1) overwrites the buffer read at iter t, so
// all waves must have finished reading tile t first. Barrier skipped once
// no future stage will touch the buffer.
// ---------------------------------------------------------------------------
__device__ __forceinline__ void stage_ab(
    const ushort_t* __restrict__ Arow, const ushort_t* __restrict__ Brow,
    int K, int k0, ushort_t* As, ushort_t* Bs, int wave, int lane)
{
    int quadS = lane & 3;
    int rr = lane >> 2;
#pragma unroll
    for (int inst = 0; inst < 2; ++inst) {
        int base_row = wave * 32 + inst * 16;
        int r = base_row + rr;
        int quadG = quadS ^ ((r >> 1) & 3);
        const ushort_t* gp = Arow + (long)r * K + k0 + quadG * 8;
        __builtin_amdgcn_global_load_lds(
            (const __attribute__((address_space(1))) unsigned int*)gp,
            (__attribute__((address_space(3))) unsigned int*)&As[base_row * 32],
            16, 0, 0);
    }
#pragma unroll
    for (int inst = 0; inst < 2; ++inst) {
        int base_row = wave * 32 + inst * 16;
        int r = base_row + rr;
        int quadG = quadS ^ ((r >> 1) & 3);
        const ushort_t* gp = Brow + (long)r * K + k0 + quadG * 8;
        __builtin_amdgcn_global_load_lds(
            (const __attribute__((address_space(1))) unsigned int*)gp,
            (__attribute__((address_space(3))) unsigned int*)&Bs[base_row * 32],
            16, 0, 0);
    }
}

__device__ __forceinline__ void gemm_body(
    ushort_t* As, ushort_t* Bs,   // flat [3*4096] each
    const ushort_t* __restrict__ A, const ushort_t* __restrict__ Wt,
    const float* __restrict__ bias, void* __restrict__ Cv,
    int M, int N, int K, int bm, int bn, bool out_bf16, bool relu)
{
    const int tid  = threadIdx.x;
    const int wave = tid >> 6;
    const int lane = tid & 63;
    const int l15  = lane & 15;
    const int quad = lane >> 4;
    const int wm   = (wave >> 1) * 64;
    const int wn   = (wave & 1) * 64;

    const ushort_t* Arow = A + (long)bm * K;
    const ushort_t* Brow = Wt + (long)bn * K;

    f32x4 acc[4][4];
#pragma unroll
    for (int i = 0; i < 4; ++i)
#pragma unroll
        for (int j = 0; j < 4; ++j) acc[i][j] = (f32x4)0.0f;

    int aoff[4], boff[4];
#pragma unroll
    for (int mi = 0; mi < 4; ++mi) {
        int r = wm + mi * 16 + l15;
        aoff[mi] = r * 32 + (quad ^ ((r >> 1) & 3)) * 8;
    }
#pragma unroll
    for (int ni = 0; ni < 4; ++ni) {
        int r = wn + ni * 16 + l15;
        boff[ni] = r * 32 + (quad ^ ((r >> 1) & 3)) * 8;
    }

    const int NT = K >> 5;   // always >= 8 here
    stage_ab(Arow, Brow, K, 0,  As,        Bs,        wave, lane);
    stage_ab(Arow, Brow, K, 32, As + 4096, Bs + 4096, wave, lane);
    int cur = 0;
    for (int t = 0; t < NT; ++t) {
        if (t + 2 < NT) {
            int nb = cur + 2; if (nb >= 3) nb -= 3;
            stage_ab(Arow, Brow, K, (t + 2) << 5,
                     As + nb * 4096, Bs + nb * 4096, wave, lane);
            // 4 loads/wave/tile; leave tiles t+1,t+2 (8 ops) in flight.
            asm volatile("s_waitcnt vmcnt(8)" ::: "memory");
        } else if (t + 2 == NT) {
            asm volatile("s_waitcnt vmcnt(4)" ::: "memory");
        } else {
            asm volatile("s_waitcnt vmcnt(0)" ::: "memory");
        }
        asm volatile("s_barrier" ::: "memory");

        const ushort_t* Ab = As + cur * 4096;
        const ushort_t* Bb = Bs + cur * 4096;
        short8 af[4], bf[4];
#pragma unroll
        for (int mi = 0; mi < 4; ++mi) af[mi] = *(const short8*)&Ab[aoff[mi]];
#pragma unroll
        for (int ni = 0; ni < 4; ++ni) bf[ni] = *(const short8*)&Bb[boff[ni]];
#pragma unroll
        for (int mi = 0; mi < 4; ++mi)
#pragma unroll
            for (int ni = 0; ni < 4; ++ni)
                acc[mi][ni] = __builtin_amdgcn_mfma_f32_16x16x32_bf16(
                    af[mi], bf[ni], acc[mi][ni], 0, 0, 0);
        // end-of-step barrier: tile t's buffer gets overwritten by
        // stage(t+3) at the top of the next iteration — every wave must be
        // done reading it first.
        if (t + 3 < NT)
            asm volatile("s_barrier" ::: "memory");
        cur = cur + 1; if (cur >= 3) cur -= 3;
    }

#pragma unroll
    for (int mi = 0; mi < 4; ++mi) {
#pragma unroll
        for (int r = 0; r < 4; ++r) {
            int row = bm + wm + mi * 16 + quad * 4 + r;
            if (row >= M) continue;
#pragma unroll
            for (int ni = 0; ni < 4; ++ni) {
                int col = bn + wn + ni * 16 + l15;
                float vv = acc[mi][ni][r] + bias[col];
                if (relu) vv = fmaxf(vv, 0.f);
                if (out_bf16)
                    ((ushort_t*)Cv)[(long)row * N + col] = f2bf(vv);
                else
                    ((float*)Cv)[(long)row * N + col] = vv;
            }
        }
    }
}

template<bool OUT_BF16, bool RELU>
__global__ __launch_bounds__(256, 3) void gemm_mfma_kernel(
    const ushort_t* __restrict__ A, const ushort_t* __restrict__ Wt,
    const float* __restrict__ bias, void* __restrict__ Cv,
    int M, int N, int K)
{
    __shared__ ushort_t As[3 * 4096];
    __shared__ ushort_t Bs[3 * 4096];
    gemm_body(As, Bs, A, Wt, bias, Cv, M, N, K,
              blockIdx.x * 128, blockIdx.y * 128, OUT_BF16, RELU);
}

// Combined val/off/attn projections. grid = (208, 5).
__global__ __launch_bounds__(256, 3) void proj_kernel(
    const ushort_t* __restrict__ qry_bf, const ushort_t* __restrict__ q_bf,
    const ushort_t* __restrict__ wt_val, const ushort_t* __restrict__ wt_off,
    const ushort_t* __restrict__ wt_attn,
    const float* __restrict__ b_val, const float* __restrict__ b_off,
    const float* __restrict__ b_attn,
    ushort_t* __restrict__ v_bf, float* __restrict__ cb, float* __restrict__ logits)
{
    __shared__ ushort_t As[3 * 4096];
    __shared__ ushort_t Bs[3 * 4096];
    int y = blockIdx.y;
    const ushort_t* A; const ushort_t* Wt; const float* bias;
    void* C; bool outbf; int N, bn;
    if (y < 2)      { A = qry_bf; Wt = wt_val;  bias = b_val;  C = v_bf;   outbf = true;  N = 256; bn = y * 128; }
    else if (y < 4) { A = q_bf;   Wt = wt_off;  bias = b_off;  C = cb;     outbf = false; N = 256; bn = (y - 2) * 128; }
    else            { A = q_bf;   Wt = wt_attn; bias = b_attn; C = logits; outbf = false; N = 128; bn = 0; }
    gemm_body(As, Bs, A, Wt, bias, C, R_ROWS, N, 256, blockIdx.x * 128, bn, outbf, false);
}

// ---------------------------------------------------------------------------
// Fused GEMM (BM=64 rows x full N=256, bf16 A, Wt [256][K]) + residual + LN.
// ---------------------------------------------------------------------------
__device__ __forceinline__ void stage_ln64(
    const ushort_t* __restrict__ Arow, const ushort_t* __restrict__ Brow,
    int K, int k0, ushort_t* As, ushort_t* Bs, int wave, int lane)
{
    int quadS = lane & 3;
    int rr = lane >> 2;
    {   // A tile: 64 rows, wave w stages rows w*16 .. w*16+15
        int base_row = wave * 16;
        int r = base_row + rr;
        int quadG = quadS ^ ((r >> 1) & 3);
        const ushort_t* gp = Arow + (long)r * K + k0 + quadG * 8;
        __builtin_amdgcn_global_load_lds(
            (const __attribute__((address_space(1))) unsigned int*)gp,
            (__attribute__((address_space(3))) unsigned int*)&As[base_row * 32],
            16, 0, 0);
    }
#pragma unroll
    for (int inst = 0; inst < 4; ++inst) {   // B tile: 256 rows, wave stages own slab
        int base_row = wave * 64 + inst * 16;
        int r = base_row + rr;
        int quadG = quadS ^ ((r >> 1) & 3);
        const ushort_t* gp = Brow + (long)r * K + k0 + quadG * 8;
        __builtin_amdgcn_global_load_lds(
            (const __attribute__((address_space(1))) unsigned int*)gp,
            (__attribute__((address_space(3))) unsigned int*)&Bs[base_row * 32],
            16, 0, 0);
    }
}

template<bool DUAL>
__global__ __launch_bounds__(256, 2) void gemm_ln_kernel(
    const ushort_t* __restrict__ A, const ushort_t* __restrict__ Wt,
    const float* __restrict__ bias, const float* __restrict__ resid,
    const float* __restrict__ gam, const float* __restrict__ bet,
    float* __restrict__ outf, ushort_t* __restrict__ outb,
    int M, int K)
{
    __shared__ ushort_t As[3 * 2048];    // 64 x 32 bf16 per buffer
    __shared__ ushort_t Bs[3 * 8192];    // 256 x 32 bf16 per buffer
    __shared__ float s1s[64][4], s2s[64][4];

    const int tid  = threadIdx.x;
    const int wave = tid >> 6;
    const int lane = tid & 63;
    const int l15  = lane & 15;
    const int quad = lane >> 4;
    const int wn   = wave * 64;
    const int bm   = blockIdx.x * 64;

    const ushort_t* Arow = A + (long)bm * K;

    float bias4[4], g4[4], be4[4];
#pragma unroll
    for (int ni = 0; ni < 4; ++ni) {
        int col = wn + ni * 16 + l15;
        bias4[ni] = bias[col];
        g4[ni]    = gam[col];
        be4[ni]   = bet[col];
    }
    float rv[4][4][4];
#pragma unroll
    for (int mi = 0; mi < 4; ++mi)
#pragma unroll
        for (int rr = 0; rr < 4; ++rr) {
            int row = bm + mi * 16 + quad * 4 + rr;
#pragma unroll
            for (int ni = 0; ni < 4; ++ni) {
                int col = wn + ni * 16 + l15;
                rv[mi][rr][ni] = (row < M) ? resid[(long)row * 256 + col] : 0.f;
            }
        }

    f32x4 acc[4][4];
#pragma unroll
    for (int i = 0; i < 4; ++i)
#pragma unroll
        for (int j = 0; j < 4; ++j) acc[i][j] = (f32x4)0.0f;

    int aoff[4], boff[4];
#pragma unroll
    for (int mi = 0; mi < 4; ++mi) {
        int r = mi * 16 + l15;
        aoff[mi] = r * 32 + (quad ^ ((r >> 1) & 3)) * 8;
    }
#pragma unroll
    for (int ni = 0; ni < 4; ++ni) {
        int r = wn + ni * 16 + l15;
        boff[ni] = r * 32 + (quad ^ ((r >> 1) & 3)) * 8;
    }

    const int NT = K >> 5;
    stage_ln64(Arow, Wt, K, 0, As, Bs, wave, lane);
    int cur = 0;
    for (int t = 0; t < NT; ++t) {
        int nxt = cur + 1; if (nxt == 3) nxt = 0;
        if (t + 1 < NT) {
            stage_ln64(Arow, Wt, K, (t + 1) << 5,
                       As + nxt * 2048, Bs + nxt * 8192, wave, lane);
            // exactly 5 loads/wave/tile: leave tile t+1 in flight
            asm volatile("s_waitcnt vmcnt(5)" ::: "memory");
        } else {
            asm volatile("s_waitcnt vmcnt(0)" ::: "memory");
        }
        asm volatile("s_barrier" ::: "memory");

        const ushort_t* Ab = As + cur * 2048;
        const ushort_t* Bb = Bs + cur * 8192;
        short8 af[4], bf[4];
#pragma unroll
        for (int mi = 0; mi < 4; ++mi) af[mi] = *(const short8*)&Ab[aoff[mi]];
#pragma unroll
        for (int ni = 0; ni < 4; ++ni) bf[ni] = *(const short8*)&Bb[boff[ni]];
#pragma unroll
        for (int mi = 0; mi < 4; ++mi)
#pragma unroll
            for (int ni = 0; ni < 4; ++ni)
                acc[mi][ni] = __builtin_amdgcn_mfma_f32_16x16x32_bf16(
                    af[mi], bf[ni], acc[mi][ni], 0, 0, 0);
        cur = nxt;
    }

    // ---- epilogue: x = acc + bias + resid; LN over the 256-col rows ----
#pragma unroll
    for (int mi = 0; mi < 4; ++mi)
#pragma unroll
        for (int rr = 0; rr < 4; ++rr) {
            float s1 = 0.f, s2 = 0.f;
#pragma unroll
            for (int ni = 0; ni < 4; ++ni) {
                float x = acc[mi][ni][rr] + bias4[ni] + rv[mi][rr][ni];
                acc[mi][ni][rr] = x;
                s1 += x; s2 += x * x;
            }
#pragma unroll
            for (int o = 1; o < 16; o <<= 1) {
                s1 += __shfl_xor(s1, o);
                s2 += __shfl_xor(s2, o);
            }
            if (l15 == 0) {
                int rl = mi * 16 + quad * 4 + rr;
                s1s[rl][wave] = s1;
                s2s[rl][wave] = s2;
            }
        }
    __syncthreads();
#pragma unroll
    for (int mi = 0; mi < 4; ++mi)
#pragma unroll
        for (int rr = 0; rr < 4; ++rr) {
            int rl  = mi * 16 + quad * 4 + rr;
            int row = bm + rl;
            float t1 = s1s[rl][0] + s1s[rl][1] + s1s[rl][2] + s1s[rl][3];
            float t2 = s2s[rl][0] + s2s[rl][1] + s2s[rl][2] + s2s[rl][3];
            float mean = t1 * (1.f / 256.f);
            float var  = t2 * (1.f / 256.f) - mean * mean;
            float inv  = rsqrtf(var + EPSF);
            if (row < M) {
#pragma unroll
                for (int ni = 0; ni < 4; ++ni) {
                    int col = wn + ni * 16 + l15;
                    float y = (acc[mi][ni][rr] - mean) * inv * g4[ni] + be4[ni];
                    outf[(long)row * 256 + col] = y;
                    if (DUAL) outb[(long)row * 256 + col] = f2bf(y);
                }
            }
        }
}

// ---------------------------------------------------------------------------
// Deformable sampling + fused softmax.
// R11: TLP instead of ILP. 8 lanes per (row,head) group — half 0 handles
// points 0..7, half 1 points 8..15 (32 gathers/thread, was 64). Softmax
// denominator and final accumulator combine across halves via shfl_xor(.,4).
// LDS meta halves to 16.9KB; launch_bounds(256,6) -> 6 blocks/CU (24
// waves/CU vs ~9 before) so TLP hides the gather latency the compiler
// refused to hide with ILP (R9/R10 nulls).
// ---------------------------------------------------------------------------
#define DEF_BLOCKS 6647   // 212704 groups / 32 per block, exact

__global__ __launch_bounds__(256, 6) void deform_sample_kernel(
    const ushort_t* __restrict__ v, const float* __restrict__ off,
    const float* __restrict__ logits, const float* __restrict__ vr,
    ushort_t* __restrict__ out)
{
    const int Hs_[4] = {100, 50, 25, 13};
    const int S0_[4] = {0, 10000, 12500, 13125};

    // 32 groups/block x 16 points x {4 weights, 4 byte-offsets}, stride 132
    __shared__ float meta[32 * 132];

    int bid = blockIdx.x;
    // bijective XCD swizzle for 6647 = 8*831 - 1 blocks:
    // wb = x*831 + y, x=bid&7 in [0,7], y=bid>>3 in [0,830] -> injective,
    // 6647 values onto [0,6646].
    int wb  = (bid & 7) * 831 + (bid >> 3);
    int grp = wb * 32 + (threadIdx.x >> 3);
    int j    = threadIdx.x & 3;          // level
    int half = (threadIdx.x >> 2) & 1;   // point-half: 0 -> pts 0..7, 1 -> 8..15
    if (grp >= R_ROWS * NHEAD) return;
    int h = grp & 7;
    int r = grp >> 3;
    int b = (r >= S_TOT) ? 1 : 0;
    int s = r - b * S_TOT;

    int lq = (s < 10000) ? 0 : (s < 12500) ? 1 : (s < 13125) ? 2 : 3;
    int t  = s - S0_[lq];
    int Wq = Hs_[lq];
    int iy = t / Wq;
    int jx = t - iy * Wq;
    float vx = vr[(b * NLVL + lq) * 2 + 0];
    float vy = vr[(b * NLVL + lq) * 2 + 1];
    float rx = (jx + 0.5f) / (vx * (float)Wq);
    float ry = (iy + 0.5f) / (vy * (float)Wq);

    const float* offp = off + (long)r * 256 + h * 32;
    // level j's 4 points = floats [j*8 .. j*8+8); this lane's 2 points:
    float4 op = ((const float4*)offp)[2 * j + half];   // (x,y,x,y) pts half*2, half*2+1
    float4 lg = ((const float4*)(logits + (long)grp * 16))[j];

    float mx = fmaxf(fmaxf(lg.x, lg.y), fmaxf(lg.z, lg.w));
    mx = fmaxf(mx, __shfl_xor(mx, 1));
    mx = fmaxf(mx, __shfl_xor(mx, 2));
    float l0 = half ? lg.z : lg.x;
    float l1 = half ? lg.w : lg.y;
    float e0 = __expf(l0 - mx), e1 = __expf(l1 - mx);
    float sl = e0 + e1;
    float s4 = sl + __shfl_xor(sl, 4);    // sum over level j's 4 points
    float sum = s4 + __shfl_xor(s4, 1);
    sum += __shfl_xor(sum, 2);            // sum over all 16
    float inv = 1.f / sum;

    const int   H  = Hs_[j];
    const float fH = (float)H;
    const int   s0 = S0_[j];
    const int   boff = b ? (S_TOT * 512) : 0;   // byte offset of batch 1
    float oxs2[2] = {op.x, op.z};
    float oys2[2] = {op.y, op.w};
    float wts2[2] = {e0 * inv, e1 * inv};

    float* mg = &meta[(threadIdx.x >> 3) * 132];
#pragma unroll
    for (int ii = 0; ii < 2; ++ii) {
        float x = rx * fH + oxs2[ii] - 0.5f;
        float y = ry * fH + oys2[ii] - 0.5f;
        float xf = floorf(x), yf = floorf(y);
        float lx = x - xf, ly = y - yf;
        int x0 = (int)xf, y0 = (int)yf;
        bool xv0 = (x0 >= 0) & (x0 < H);
        bool xv1 = (x0 >= -1) & (x0 < H - 1);
        bool yv0 = (y0 >= 0) & (y0 < H);
        bool yv1 = (y0 >= -1) & (y0 < H - 1);
        float w = wts2[ii];
        f32x4 w4;
        w4.x = (xv0 & yv0) ? (1.f - lx) * (1.f - ly) * w : 0.f;
        w4.y = (xv1 & yv0) ? lx * (1.f - ly) * w : 0.f;
        w4.z = (xv0 & yv1) ? (1.f - lx) * ly * w : 0.f;
        w4.w = (xv1 & yv1) ? lx * ly * w : 0.f;
        int xc0 = min(max(x0, 0), H - 1), xc1 = min(max(x0 + 1, 0), H - 1);
        int yc0 = min(max(y0, 0), H - 1), yc1 = min(max(y0 + 1, 0), H - 1);
        int4 o4;
        o4.x = ((s0 + yc0 * H + xc0) << 9) + boff;
        o4.y = ((s0 + yc0 * H + xc1) << 9) + boff;
        o4.z = ((s0 + yc1 * H + xc0) << 9) + boff;
        o4.w = ((s0 + yc1 * H + xc1) << 9) + boff;
        // slot pt = point*4 + level = (half*2+ii)*4 + j = 8*half + 4*ii + j
        int pt = 8 * half + 4 * ii + j;
        *(f32x4*)&mg[pt * 8]     = w4;
        *(int4*) &mg[pt * 8 + 4] = o4;
    }
    // all 8 producer lanes of this group are in the same wave
    asm volatile("s_waitcnt lgkmcnt(0)" ::: "memory");

    const char* vbase = (const char*)v;
    const unsigned loff = (unsigned)(h * 64 + j * 16);   // this lane's 16B slot
    f32x2 acc2[4];
#pragma unroll
    for (int c = 0; c < 4; ++c) acc2[c] = (f32x2)0.0f;

#define FMA4(G, WGT) do {                                                    \
        unsigned uu0 = (G).x, uu1 = (G).y, uu2 = (G).z, uu3 = (G).w;         \
        f32x2 gv;                                                            \
        gv.x = __builtin_bit_cast(float, uu0 << 16);                         \
        gv.y = __builtin_bit_cast(float, uu0 & 0xFFFF0000u);                 \
        acc2[0] += gv * (WGT);                                               \
        gv.x = __builtin_bit_cast(float, uu1 << 16);                         \
        gv.y = __builtin_bit_cast(float, uu1 & 0xFFFF0000u);                 \
        acc2[1] += gv * (WGT);                                               \
        gv.x = __builtin_bit_cast(float, uu2 << 16);                         \
        gv.y = __builtin_bit_cast(float, uu2 & 0xFFFF0000u);                 \
        acc2[2] += gv * (WGT);                                               \
        gv.x = __builtin_bit_cast(float, uu3 << 16);                         \
        gv.y = __builtin_bit_cast(float, uu3 & 0xFFFF0000u);                 \
        acc2[3] += gv * (WGT);                                               \
    } while (0)

    // this half consumes its 8 points (slots half*8 .. half*8+7)
    const float* ms = &mg[half * 64];
#pragma unroll
    for (int m = 0; m < 8; ++m) {
        f32x4 w4 = *(const f32x4*)&ms[m * 8];
        int4  o4 = *(const int4*) &ms[m * 8 + 4];
        uint4 g0 = *(const uint4*)(vbase + ((unsigned)o4.x + loff));
        uint4 g1 = *(const uint4*)(vbase + ((unsigned)o4.y + loff));
        uint4 g2 = *(const uint4*)(vbase + ((unsigned)o4.z + loff));
        uint4 g3 = *(const uint4*)(vbase + ((unsigned)o4.w + loff));
        FMA4(g0, w4.x); FMA4(g1, w4.y); FMA4(g2, w4.z); FMA4(g3, w4.w);
    }
#undef FMA4

    // combine the two halves (lane k <-> k^4 have same (group, j))
#pragma unroll
    for (int c = 0; c < 4; ++c) {
        acc2[c].x += __shfl_xor(acc2[c].x, 4);
        acc2[c].y += __shfl_xor(acc2[c].y, 4);
    }
    if (half == 0) {
        uint4 o;
        o.x = (unsigned)f2bf(acc2[0].x) | ((unsigned)f2bf(acc2[0].y) << 16);
        o.y = (unsigned)f2bf(acc2[1].x) | ((unsigned)f2bf(acc2[1].y) << 16);
        o.z = (unsigned)f2bf(acc2[2].x) | ((unsigned)f2bf(acc2[2].y) << 16);
        o.w = (unsigned)f2bf(acc2[3].x) | ((unsigned)f2bf(acc2[3].y) << 16);
        *(uint4*)&out[(long)r * 256 + h * 32 + j * 8] = o;
    }
}

// ---------------------------------------------------------------------------
extern "C" void kernel_launch(void* const* d_in, const int* in_sizes, int n_in,
                              void* d_out, int out_size, void* d_ws, size_t ws_size,
                              hipStream_t stream)
{
    const float* query  = (const float*)d_in[0];
    const float* qpos   = (const float*)d_in[1];
    const float* vr     = (const float*)d_in[2];
    const float* W_off  = (const float*)d_in[5];
    const float* b_off  = (const float*)d_in[6];
    const float* W_attn = (const float*)d_in[7];
    const float* b_attn = (const float*)d_in[8];
    const float* W_val  = (const float*)d_in[9];
    const float* b_val  = (const float*)d_in[10];
    const float* W_out  = (const float*)d_in[11];
    const float* b_out  = (const float*)d_in[12];
    const float* ln1g   = (const float*)d_in[13];
    const float* ln1b   = (const float*)d_in[14];
    const float* W1     = (const float*)d_in[15];
    const float* b1     = (const float*)d_in[16];
    const float* W2     = (const float*)d_in[17];
    const float* b2     = (const float*)d_in[18];
    const float* ln2g   = (const float*)d_in[19];
    const float* ln2b   = (const float*)d_in[20];
    float* out = (float*)d_out;

    float* ws = (float*)d_ws;
    const long R128 = (long)R_ROWS * 128;
    ushort_t* q_bf    = (ushort_t*)(ws);                 // R x 256 bf16
    ushort_t* qry_bf  = (ushort_t*)(ws + R128);          // R x 256 bf16
    ushort_t* v_bf    = (ushort_t*)(ws + 2 * R128);      // R x 256 bf16
    float*    logits  = ws + 3 * R128;                   // R x 128 f32
    ushort_t* h_bf    = (ushort_t*)(ws);                 // R x 1024 bf16 (overlays above, FF stage)
    float*    cb      = ws + 4 * R128;                   // R x 256 f32: off
    ushort_t* samp_bf = (ushort_t*)(ws + 6 * R128);      // R x 256 bf16: sampled -> x_bf
    float*    xb      = ws + 7 * R128;                   // R x 256 f32: x (LN1 out)
    ushort_t* wt      = (ushort_t*)(ws + 9 * R128);
    ushort_t* wt_val  = wt;                 // 256x256
    ushort_t* wt_off  = wt + 65536;         // 256x256
    ushort_t* wt_attn = wt + 131072;        // 128x256
    ushort_t* wt_out  = wt + 163840;        // 256x256
    ushort_t* wt_w1   = wt + 229376;        // 1024x256
    ushort_t* wt_w2   = wt + 491520;        // 256x1024

    dim3 blk(256);
    const int MB128 = (R_ROWS + 127) / 128;   // 208
    const int MB64  = (R_ROWS + 63) / 64;     // 416

    // 1. prep: weight transposes + q/qsum bf16 conversion
    prep_kernel<<<736 + R_ROWS / 4, blk, 0, stream>>>(
        W_val, W_off, W_attn, W_out, W1, W2,
        wt_val, wt_off, wt_attn, wt_out, wt_w1, wt_w2,
        query, qpos, qry_bf, q_bf);
    // 2. val + off + attn projections
    proj_kernel<<<dim3(MB128, 5), blk, 0, stream>>>(
        qry_bf, q_bf, wt_val, wt_off, wt_attn, b_val, b_off, b_attn,
        v_bf, cb, logits);
    // 3. deformable sampling (+softmax) -> samp_bf
    deform_sample_kernel<<<DEF_BLOCKS, blk, 0, stream>>>(
        v_bf, cb, logits, vr, samp_bf);
    // 4. x = LN(query + samp @ W_out + b_out) -> xb (f32) + samp_bf (bf16)
    gemm_ln_kernel<true><<<MB64, blk, 0, stream>>>(
        samp_bf, wt_out, b_out, query, ln1g, ln1b, xb, samp_bf, R_ROWS, 256);
    // 5. h = relu(x @ W1 + b1) -> h_bf
    gemm_mfma_kernel<true, true><<<dim3(MB128, 8), blk, 0, stream>>>(
        samp_bf, wt_w1, b1, h_bf, R_ROWS, 1024, 256);
    // 6. out = LN(x + h @ W2 + b2)
    gemm_ln_kernel<false><<<MB64, blk, 0, stream>>>(
        h_bf, wt_w2, b2, xb, ln2g, ln2b, out, nullptr, R_ROWS, 1024);
}